// Round 5
// baseline (463.588 us; speedup 1.0000x reference)
//
#include <hip/hip_runtime.h>
#include <hip/hip_fp16.h>
#include <math.h>

typedef _Float16 f16;
typedef _Float16 f16x4 __attribute__((ext_vector_type(4)));
typedef _Float16 f16x8 __attribute__((ext_vector_type(8)));
typedef float f32x4 __attribute__((ext_vector_type(4)));

#define GLOAD_LDS16(g, l)                                                                  \
    __builtin_amdgcn_global_load_lds((const __attribute__((address_space(1))) void*)(g),   \
                                     (__attribute__((address_space(3))) void*)(l), 16, 0, 0)

// ---- shared MFMA compute step: 128x128 tile, BK=32, 4 waves (2x2), 4x4 frags/wave ----
__device__ __forceinline__ void mma_step(const f16* __restrict__ As, const f16* __restrict__ Bs,
                                         f32x4 acc[4][4], int wr, int wc, int l)
{
    f16x8 a[4], b[4];
    const int lr = l & 15, lk = (l >> 4) * 8;
#pragma unroll
    for (int m = 0; m < 4; m++) a[m] = *(const f16x8*)&As[(wr * 64 + m * 16 + lr) * 32 + lk];
#pragma unroll
    for (int n = 0; n < 4; n++) b[n] = *(const f16x8*)&Bs[(wc * 64 + n * 16 + lr) * 32 + lk];
#pragma unroll
    for (int m = 0; m < 4; m++)
#pragma unroll
        for (int n = 0; n < 4; n++)
            acc[m][n] = __builtin_amdgcn_mfma_f32_16x16x32_f16(a[m], b[n], acc[m][n], 0, 0, 0);
}

// f32 -> f16 cast, vectorized float4 -> f16x4, grid-stride.
__global__ __launch_bounds__(256) void cast_kernel(const float* __restrict__ src,
                                                   f16* __restrict__ dst, int n4)
{
    const int stride = gridDim.x * blockDim.x;
    for (int i = blockIdx.x * blockDim.x + threadIdx.x; i < n4; i += stride) {
        float4 v = *(const float4*)(src + (long long)i * 4);
        *(f16x4*)(dst + (long long)i * 4) = (f16x4){(f16)v.x, (f16)v.y, (f16)v.z, (f16)v.w};
    }
}

// Three-source f32 -> f16 cast (for Wq/Wk/Wv), blockIdx.z selects source.
__global__ __launch_bounds__(256) void cast3_kernel(const float* __restrict__ s0,
                                                    const float* __restrict__ s1,
                                                    const float* __restrict__ s2,
                                                    f16* __restrict__ dst, int n4each)
{
    const int z = blockIdx.z;
    const float* src = (z == 0) ? s0 : (z == 1) ? s1 : s2;
    f16* d = dst + (long long)z * n4each * 4;
    const int stride = gridDim.x * blockDim.x;
    for (int i = blockIdx.x * blockDim.x + threadIdx.x; i < n4each; i += stride) {
        float4 v = *(const float4*)(src + (long long)i * 4);
        *(f16x4*)(d + (long long)i * 4) = (f16x4){(f16)v.x, (f16)v.y, (f16)v.z, (f16)v.w};
    }
}

// Batched NT GEMM, fp16 in: C[M,N] = A[M,K] * B[N,K]^T.
// T3/T4: 3 staging buffers, prefetch depth 2, counted vmcnt(4) across raw s_barrier
// (never drain to 0 in steady state).  global_load_lds staging, XCD swizzle.
// Grid: dim3(nwg_xy, 1, nz); gx = column-block count; nwg_xy must be % 8 == 0.
template <int OUTF16>
__global__ __launch_bounds__(256, 3) void gemm_nt_kernel(
    const f16* __restrict__ Ab, const f16* __restrict__ Bb, void* __restrict__ Cb,
    int K, int lda, int ldb, int ldc,
    long long sA, long long sB, long long sC, int gx)
{
    __shared__ f16 As[3][128 * 32];
    __shared__ f16 Bs[3][128 * 32];

    // XCD-aware bijective swizzle (nwg % 8 == 0 guaranteed by caller).
    const int nwg = gridDim.x;
    const int swz = (blockIdx.x & 7) * (nwg >> 3) + (blockIdx.x >> 3);
    const int bx = swz % gx;
    const int by = swz / gx;

    const int z = blockIdx.z;
    const f16* A  = Ab + z * sA + (long long)by * 128 * lda;
    const f16* Bm = Bb + z * sB + (long long)bx * 128 * ldb;

    const int tid = threadIdx.x;
    const int w = tid >> 6, l = tid & 63;
    const int wr = w >> 1, wc = w & 1;
    const int srow = l >> 2, skc = (l & 3) * 8;

    // per-thread staging source bases (row = w*32 + i*16 + srow, col = skc)
    const f16* a0 = A  + (long long)(w * 32 + srow) * lda + skc;
    const f16* b0 = Bm + (long long)(w * 32 + srow) * ldb + skc;

    f32x4 acc[4][4];
#pragma unroll
    for (int i = 0; i < 4; i++)
#pragma unroll
        for (int j = 0; j < 4; j++) acc[i][j] = (f32x4){0.f, 0.f, 0.f, 0.f};

    // 4 global_load_lds per thread per STAGE -> 4 vmcnt ticks per wave per STAGE.
#define STAGE(c, kt)                                                              \
    do {                                                                          \
        _Pragma("unroll")                                                         \
        for (int i_ = 0; i_ < 2; i_++) {                                          \
            GLOAD_LDS16(a0 + (long long)i_ * 16 * lda + (kt), &As[c][(w * 2 + i_) * 512]); \
            GLOAD_LDS16(b0 + (long long)i_ * 16 * ldb + (kt), &Bs[c][(w * 2 + i_) * 512]); \
        }                                                                         \
    } while (0)

    const int nt = K / 32;   // >= 4 for all call sites (32 or 64)

    // Prologue: stage tiles 0 and 1; wait only for tile 0 (vmcnt(4) leaves tile 1
    // in flight); raw barrier publishes buf0 to all waves.
    STAGE(0, 0);
    STAGE(1, 32);
    asm volatile("s_waitcnt vmcnt(4)");
    __builtin_amdgcn_s_barrier();
    __builtin_amdgcn_sched_barrier(0);

    for (int t = 0; t < nt; ++t) {
        const int have_next = (t + 2 < nt);
        if (have_next) STAGE((t + 2) % 3, (t + 2) * 32);  // prefetch 2 tiles ahead
        mma_step(As[t % 3], Bs[t % 3], acc, wr, wc, l);
        // RAW: before iter t+1 reads buf[(t+1)%3] (staged at iter t-1), ensure its
        // loads landed.  If we just staged tile t+2 (4 newest loads), vmcnt(4)
        // exactly excludes them; otherwise drain (tail).
        if (have_next) asm volatile("s_waitcnt vmcnt(4)");
        else           asm volatile("s_waitcnt vmcnt(0)");
        // WAR: barrier ensures all waves finished reading buf[t%3] before iter t+1
        // overwrites it (its STAGE targets (t+3)%3 == t%3).
        __builtin_amdgcn_s_barrier();
        __builtin_amdgcn_sched_barrier(0);
    }
#undef STAGE

    const int col = l & 15, ro = (l >> 4) * 4;
    const long long r0 = (long long)by * 128 + wr * 64;
    const int c0 = bx * 128 + wc * 64;
    if (OUTF16) {
        f16* C = (f16*)Cb + z * sC;
#pragma unroll
        for (int m = 0; m < 4; m++)
#pragma unroll
            for (int n = 0; n < 4; n++)
#pragma unroll
                for (int i = 0; i < 4; i++)
                    C[(r0 + m * 16 + ro + i) * ldc + c0 + n * 16 + col] = (f16)acc[m][n][i];
    } else {
        float* C = (float*)Cb + z * sC;
#pragma unroll
        for (int m = 0; m < 4; m++)
#pragma unroll
            for (int n = 0; n < 4; n++)
#pragma unroll
                for (int i = 0; i < 4; i++)
                    C[(r0 + m * 16 + ro + i) * ldc + c0 + n * 16 + col] = acc[m][n][i];
    }
}

// vT[b][o][s] = v[b][s][o], 64x64 LDS tiles.
__global__ __launch_bounds__(256) void transpose_v_kernel(const f16* __restrict__ v, f16* __restrict__ vT)
{
    __shared__ f16 tile[64][72];
    const int b = blockIdx.z;
    const int s0 = blockIdx.x * 64, o0 = blockIdx.y * 64;
    const int t = threadIdx.x;
    const int r = t >> 2, c = (t & 3) * 16;
    const f16* src = v + ((long long)b * 2048 + s0) * 1024 + o0;
    *(f16x8*)&tile[r][c]     = *(const f16x8*)(src + (long long)r * 1024 + c);
    *(f16x8*)&tile[r][c + 8] = *(const f16x8*)(src + (long long)r * 1024 + c + 8);
    __syncthreads();
    f16* dst = vT + ((long long)b * 1024 + o0) * 2048 + s0;
    f16 buf[16];
#pragma unroll
    for (int j = 0; j < 16; j++) buf[j] = tile[c + j][r];
    *(f16x8*)(dst + (long long)r * 2048 + c)     = *(f16x8*)&buf[0];
    *(f16x8*)(dst + (long long)r * 2048 + c + 8) = *(f16x8*)&buf[8];
}

__device__ __forceinline__ float wred_max(float v) {
#pragma unroll
    for (int o = 32; o > 0; o >>= 1) v = fmaxf(v, __shfl_xor(v, o));
    return v;
}
__device__ __forceinline__ float wred_sum(float v) {
#pragma unroll
    for (int o = 32; o > 0; o >>= 1) v += __shfl_xor(v, o);
    return v;
}

// In-place masked softmax over each 2048-wide score row (fp16).
__global__ __launch_bounds__(256) void softmax_kernel(f16* __restrict__ Sm, const int* __restrict__ mask)
{
    const long long row = blockIdx.x;
    const int b = (int)(row >> 11);
    f16* Srow = Sm + row * 2048;
    const int* mrow = mask + b * 2048;
    const int t = threadIdx.x;
    const int w = t >> 6, l = t & 63;

    f16x8 sv = *(const f16x8*)(Srow + t * 8);
    int4 m0 = *(const int4*)(mrow + t * 8);
    int4 m1 = *(const int4*)(mrow + t * 8 + 4);
    int mk[8] = {m0.x, m0.y, m0.z, m0.w, m1.x, m1.y, m1.z, m1.w};
    float v[8];
#pragma unroll
    for (int j = 0; j < 8; j++) v[j] = (float)sv[j];

    float mx = -INFINITY;
#pragma unroll
    for (int j = 0; j < 8; j++) if (mk[j]) mx = fmaxf(mx, v[j]);
    mx = wred_max(mx);
    __shared__ float redm[4], reds[4];
    if (l == 0) redm[w] = mx;
    __syncthreads();
    mx = fmaxf(fmaxf(redm[0], redm[1]), fmaxf(redm[2], redm[3]));

    if (mx == -INFINITY) {
        // reference: all scores == MASK_FILL -> softmax is exactly uniform
        const f16 u = (f16)(1.0f / 2048.0f);
        f16x8 pv;
#pragma unroll
        for (int j = 0; j < 8; j++) pv[j] = u;
        *(f16x8*)(Srow + t * 8) = pv;
        return;
    }

    float e[8];
    float s = 0.f;
#pragma unroll
    for (int j = 0; j < 8; j++) { e[j] = mk[j] ? expf(v[j] - mx) : 0.f; s += e[j]; }
    s = wred_sum(s);
    if (l == 0) reds[w] = s;
    __syncthreads();
    s = reds[0] + reds[1] + reds[2] + reds[3];
    const float inv = 1.0f / s;
    f16x8 pv;
#pragma unroll
    for (int j = 0; j < 8; j++) pv[j] = (f16)(e[j] * inv);
    *(f16x8*)(Srow + t * 8) = pv;
}

extern "C" void kernel_launch(void* const* d_in, const int* in_sizes, int n_in,
                              void* d_out, int out_size, void* d_ws, size_t ws_size,
                              hipStream_t stream)
{
    const float* query = (const float*)d_in[0];
    const float* keyi  = (const float*)d_in[1];
    const float* value = (const float*)d_in[2];
    const float* Wq    = (const float*)d_in[3];
    const float* Wk    = (const float*)d_in[4];
    const float* Wv    = (const float*)d_in[5];
    const int*   mask  = (const int*)d_in[6];
    float* out = (float*)d_out;

    // ws layout (fp16 elements), total exactly 5*SH*2B = 167.8 MB (proven footprint):
    //   [Xbuf: 0..SH) [v: SH..2SH) [q: 2SH..3SH) [k: 3SH..4SH) [vT: 4SH..5SH)
    //   wh (f16 W's, 3*1M elems) lives at the START of the vT slot (dead before
    //   transpose runs).  P aliases [0..2SH) = Xbuf+v (both dead by S-GEMM time).
    const long long SH = (long long)8 * 2048 * 1024;
    f16* Xbuf = (f16*)d_ws;
    f16* vb   = Xbuf + SH;
    f16* qb   = Xbuf + 2 * SH;
    f16* kb   = Xbuf + 3 * SH;
    f16* vTb  = Xbuf + 4 * SH;
    f16* wh   = vTb;   // 3 * 1048576 f16 = 6 MB, overwritten later by vT
    f16* Pb   = Xbuf;  // 8*2048*2048 fp16 = 2*SH

    const int n4x = (int)(SH / 4);      // float4 count per 16M-elem input
    const int n4w = 1024 * 1024 / 4;    // float4 count per W
    const long long zero = 0;

    // 0) W -> f16 (6 MB total)
    cast3_kernel<<<dim3(128, 1, 3), 256, 0, stream>>>(Wq, Wk, Wv, wh, n4w);

    // 1) per input: cast X -> f16, then counted-vmcnt f16 NT GEMM (gx=8)
    const float* Xs[3] = {query, keyi, value};
    f16* Os[3] = {qb, kb, vb};
    for (int z = 0; z < 3; z++) {
        cast_kernel<<<dim3(2048), 256, 0, stream>>>(Xs[z], Xbuf, n4x);
        gemm_nt_kernel<1><<<dim3(1024, 1, 1), 256, 0, stream>>>(
            Xbuf, wh + (long long)z * 1024 * 1024, (void*)Os[z],
            1024, 1024, 1024, 1024, zero, zero, zero, 8);
    }
    // 2) v -> vT (overwrites wh region; wh is dead by now)
    transpose_v_kernel<<<dim3(32, 16, 8), 256, 0, stream>>>(vb, vTb);
    // 3) S = q @ k^T per batch  (16x16 blocks per z, gx=16)
    gemm_nt_kernel<1><<<dim3(256, 1, 8), 256, 0, stream>>>(
        qb, kb, (void*)Pb, 1024, 1024, 1024, 2048,
        (long long)2048 * 1024, (long long)2048 * 1024, (long long)2048 * 2048, 16);
    // 4) P = masked softmax(S), in place
    softmax_kernel<<<dim3(16384), 256, 0, stream>>>(Pb, mask);
    // 5) context = P @ vT^T  (f32 out; 8x16 blocks per z, gx=8)
    gemm_nt_kernel<0><<<dim3(128, 1, 8), 256, 0, stream>>>(
        Pb, vTb, (void*)out, 2048, 2048, 2048, 1024,
        (long long)2048 * 2048, (long long)1024 * 2048, (long long)2048 * 1024, 8);
}

// Round 6
// 425.049 us; speedup vs baseline: 1.0907x; 1.0907x over previous
//
#include <hip/hip_runtime.h>
#include <hip/hip_fp16.h>
#include <math.h>

typedef _Float16 f16;
typedef _Float16 f16x4 __attribute__((ext_vector_type(4)));
typedef _Float16 f16x8 __attribute__((ext_vector_type(8)));
typedef float f32x16 __attribute__((ext_vector_type(16)));

#define GLOAD_LDS16(g, l)                                                                  \
    __builtin_amdgcn_global_load_lds((const __attribute__((address_space(1))) void*)(g),   \
                                     (__attribute__((address_space(3))) void*)(l), 16, 0, 0)

// ---- MFMA compute step: 128x128 tile, BK=32, 4 waves (2x2), 2x2 32x32 frags/wave ----
// 32x32x16_f16 frags: A/B lane l -> row/col = l&31, k = (l>>5)*8 + 0..7 (f16x8, 1 ds_read_b128).
__device__ __forceinline__ void mma_step(const f16* __restrict__ As, const f16* __restrict__ Bs,
                                         f32x16 acc[2][2], int wr, int wc, int l)
{
    const int lr = l & 31, lk = (l >> 5) * 8;
    f16x8 a[2][2], b[2][2];
#pragma unroll
    for (int m = 0; m < 2; m++)
#pragma unroll
        for (int kk = 0; kk < 2; kk++)
            a[m][kk] = *(const f16x8*)&As[(wr * 64 + m * 32 + lr) * 32 + kk * 16 + lk];
#pragma unroll
    for (int n = 0; n < 2; n++)
#pragma unroll
        for (int kk = 0; kk < 2; kk++)
            b[n][kk] = *(const f16x8*)&Bs[(wc * 64 + n * 32 + lr) * 32 + kk * 16 + lk];
#pragma unroll
    for (int m = 0; m < 2; m++)
#pragma unroll
        for (int n = 0; n < 2; n++)
#pragma unroll
            for (int kk = 0; kk < 2; kk++)
                acc[m][n] = __builtin_amdgcn_mfma_f32_32x32x16_f16(a[m][kk], b[n][kk], acc[m][n], 0, 0, 0);
}

// Three-source f32 -> f16 cast with independent destinations, blockIdx.z selects.
__global__ __launch_bounds__(256) void cast3_kernel(const float* __restrict__ s0,
                                                    const float* __restrict__ s1,
                                                    const float* __restrict__ s2,
                                                    f16* d0, f16* d1, f16* d2, int n4each)
{
    const int z = blockIdx.z;
    const float* src = (z == 0) ? s0 : (z == 1) ? s1 : s2;
    f16* d = (z == 0) ? d0 : (z == 1) ? d1 : d2;
    const int stride = gridDim.x * blockDim.x;
    for (int i = blockIdx.x * blockDim.x + threadIdx.x; i < n4each; i += stride) {
        float4 v = *(const float4*)(src + (long long)i * 4);
        *(f16x4*)(d + (long long)i * 4) = (f16x4){(f16)v.x, (f16)v.y, (f16)v.z, (f16)v.w};
    }
}

// Batched NT GEMM, fp16 in: C[M,N] = A[M,K] * B[N,K]^T.
// Round-4 proven 2-slot double-buffer schedule; 32x32x16 MFMA; XCD swizzle.
// Grid: dim3(nwg_xy, 1, nz); gx = column-block count; nwg_xy must be % 8 == 0.
template <int OUTF16>
__global__ __launch_bounds__(256, 4) void gemm_nt_kernel(
    const f16* __restrict__ Ab, const f16* __restrict__ Bb, void* __restrict__ Cb,
    int K, int lda, int ldb, int ldc,
    long long sA, long long sB, long long sC, int gx)
{
    __shared__ f16 As[2][128 * 32];
    __shared__ f16 Bs[2][128 * 32];

    // XCD-aware bijective swizzle (nwg % 8 == 0 guaranteed by caller).
    const int nwg = gridDim.x;
    const int swz = (blockIdx.x & 7) * (nwg >> 3) + (blockIdx.x >> 3);
    const int bx = swz % gx;
    const int by = swz / gx;

    const int z = blockIdx.z;
    const f16* A  = Ab + z * sA + (long long)by * 128 * lda;
    const f16* Bm = Bb + z * sB + (long long)bx * 128 * ldb;

    const int tid = threadIdx.x;
    const int w = tid >> 6, l = tid & 63;
    const int wr = w >> 1, wc = w & 1;
    const int srow = l >> 2, skc = (l & 3) * 8;

    // per-thread staging source bases (row = w*32 + i*16 + srow, col = skc)
    const f16* a0 = A  + (long long)(w * 32 + srow) * lda + skc;
    const f16* b0 = Bm + (long long)(w * 32 + srow) * ldb + skc;

    f32x16 acc[2][2];
#pragma unroll
    for (int i = 0; i < 2; i++)
#pragma unroll
        for (int j = 0; j < 2; j++)
#pragma unroll
            for (int r = 0; r < 16; r++) acc[i][j][r] = 0.f;

#define STAGE(c, kt)                                                              \
    do {                                                                          \
        _Pragma("unroll")                                                         \
        for (int i_ = 0; i_ < 2; i_++) {                                          \
            GLOAD_LDS16(a0 + (long long)i_ * 16 * lda + (kt), &As[c][(w * 2 + i_) * 512]); \
            GLOAD_LDS16(b0 + (long long)i_ * 16 * ldb + (kt), &Bs[c][(w * 2 + i_) * 512]); \
        }                                                                         \
    } while (0)

    const int nt = K / 32;
    STAGE(0, 0);
    asm volatile("s_waitcnt vmcnt(0)");
    __syncthreads();
    int cur = 0;
    for (int t = 0; t < nt - 1; ++t) {
        STAGE(cur ^ 1, (t + 1) * 32);      // prefetch next tile into other buffer
        mma_step(As[cur], Bs[cur], acc, wr, wc, l);
        asm volatile("s_waitcnt vmcnt(0)");
        __syncthreads();
        cur ^= 1;
    }
    mma_step(As[cur], Bs[cur], acc, wr, wc, l);
#undef STAGE

    // 32x32 C/D layout (HW-verified): col = lane&31, row = (r&3) + 8*(r>>2) + 4*(lane>>5)
    const int col = l & 31, rb = 4 * (l >> 5);
    const long long r0 = (long long)by * 128 + wr * 64;
    const int c0 = bx * 128 + wc * 64;
    if (OUTF16) {
        f16* C = (f16*)Cb + z * sC;
#pragma unroll
        for (int m = 0; m < 2; m++)
#pragma unroll
            for (int n = 0; n < 2; n++)
#pragma unroll
                for (int r = 0; r < 16; r++) {
                    const int row = (r & 3) + 8 * (r >> 2) + rb;
                    C[(r0 + m * 32 + row) * ldc + c0 + n * 32 + col] = (f16)acc[m][n][r];
                }
    } else {
        float* C = (float*)Cb + z * sC;
#pragma unroll
        for (int m = 0; m < 2; m++)
#pragma unroll
            for (int n = 0; n < 2; n++)
#pragma unroll
                for (int r = 0; r < 16; r++) {
                    const int row = (r & 3) + 8 * (r >> 2) + rb;
                    C[(r0 + m * 32 + row) * ldc + c0 + n * 32 + col] = acc[m][n][r];
                }
    }
}

// vT[b][o][s] = v[b][s][o], 64x64 LDS tiles.
__global__ __launch_bounds__(256) void transpose_v_kernel(const f16* __restrict__ v, f16* __restrict__ vT)
{
    __shared__ f16 tile[64][72];
    const int b = blockIdx.z;
    const int s0 = blockIdx.x * 64, o0 = blockIdx.y * 64;
    const int t = threadIdx.x;
    const int r = t >> 2, c = (t & 3) * 16;
    const f16* src = v + ((long long)b * 2048 + s0) * 1024 + o0;
    *(f16x8*)&tile[r][c]     = *(const f16x8*)(src + (long long)r * 1024 + c);
    *(f16x8*)&tile[r][c + 8] = *(const f16x8*)(src + (long long)r * 1024 + c + 8);
    __syncthreads();
    f16* dst = vT + ((long long)b * 1024 + o0) * 2048 + s0;
    f16 buf[16];
#pragma unroll
    for (int j = 0; j < 16; j++) buf[j] = tile[c + j][r];
    *(f16x8*)(dst + (long long)r * 2048 + c)     = *(f16x8*)&buf[0];
    *(f16x8*)(dst + (long long)r * 2048 + c + 8) = *(f16x8*)&buf[8];
}

__device__ __forceinline__ float wred_max(float v) {
#pragma unroll
    for (int o = 32; o > 0; o >>= 1) v = fmaxf(v, __shfl_xor(v, o));
    return v;
}
__device__ __forceinline__ float wred_sum(float v) {
#pragma unroll
    for (int o = 32; o > 0; o >>= 1) v += __shfl_xor(v, o);
    return v;
}

// In-place masked softmax over each 2048-wide score row (fp16).
__global__ __launch_bounds__(256) void softmax_kernel(f16* __restrict__ Sm, const int* __restrict__ mask)
{
    const long long row = blockIdx.x;
    const int b = (int)(row >> 11);
    f16* Srow = Sm + row * 2048;
    const int* mrow = mask + b * 2048;
    const int t = threadIdx.x;
    const int w = t >> 6, l = t & 63;

    f16x8 sv = *(const f16x8*)(Srow + t * 8);
    int4 m0 = *(const int4*)(mrow + t * 8);
    int4 m1 = *(const int4*)(mrow + t * 8 + 4);
    int mk[8] = {m0.x, m0.y, m0.z, m0.w, m1.x, m1.y, m1.z, m1.w};
    float v[8];
#pragma unroll
    for (int j = 0; j < 8; j++) v[j] = (float)sv[j];

    float mx = -INFINITY;
#pragma unroll
    for (int j = 0; j < 8; j++) if (mk[j]) mx = fmaxf(mx, v[j]);
    mx = wred_max(mx);
    __shared__ float redm[4], reds[4];
    if (l == 0) redm[w] = mx;
    __syncthreads();
    mx = fmaxf(fmaxf(redm[0], redm[1]), fmaxf(redm[2], redm[3]));

    if (mx == -INFINITY) {
        // reference: all scores == MASK_FILL -> softmax is exactly uniform
        const f16 u = (f16)(1.0f / 2048.0f);
        f16x8 pv;
#pragma unroll
        for (int j = 0; j < 8; j++) pv[j] = u;
        *(f16x8*)(Srow + t * 8) = pv;
        return;
    }

    float e[8];
    float s = 0.f;
#pragma unroll
    for (int j = 0; j < 8; j++) { e[j] = mk[j] ? expf(v[j] - mx) : 0.f; s += e[j]; }
    s = wred_sum(s);
    if (l == 0) reds[w] = s;
    __syncthreads();
    s = reds[0] + reds[1] + reds[2] + reds[3];
    const float inv = 1.0f / s;
    f16x8 pv;
#pragma unroll
    for (int j = 0; j < 8; j++) pv[j] = (f16)(e[j] * inv);
    *(f16x8*)(Srow + t * 8) = pv;
}

extern "C" void kernel_launch(void* const* d_in, const int* in_sizes, int n_in,
                              void* d_out, int out_size, void* d_ws, size_t ws_size,
                              hipStream_t stream)
{
    const float* query = (const float*)d_in[0];
    const float* keyi  = (const float*)d_in[1];
    const float* value = (const float*)d_in[2];
    const float* Wq    = (const float*)d_in[3];
    const float* Wk    = (const float*)d_in[4];
    const float* Wv    = (const float*)d_in[5];
    const int*   mask  = (const int*)d_in[6];
    float* out = (float*)d_out;

    // ws: 5 slots of SH f16 = 167.8 MB (proven footprint).
    //   slot0: Xk, then v (v-proj output), then P-low
    //   slot1: Xv, then P-high
    //   slot2: q
    //   slot3: Xq, then k
    //   slot4: wh (Wq/Wk/Wv f16, 6 MB) then vT
    // Order guarantees write-before-read with no overlap of live data:
    //   cast3(W)->wh; cast3(X)->{s3,s0,s1}; q=NT(s3,Wqh)->s2; k=NT(s0,Wkh)->s3;
    //   v=NT(s1,Wvh)->s0; vT=transpose(s0)->s4 (kills wh, dead);
    //   S=NT(s2,s3)->P(s0|s1) (kills v,Xv — both dead); softmax; out=NT(P,vT).
    const long long SH = (long long)8 * 2048 * 1024;
    f16* slot0 = (f16*)d_ws;
    f16* slot1 = slot0 + SH;
    f16* slot2 = slot0 + 2 * SH;
    f16* slot3 = slot0 + 3 * SH;
    f16* slot4 = slot0 + 4 * SH;
    f16* wh    = slot4;            // 3 * 1048576 f16 = 6 MB, dead before transpose
    f16* Pb    = slot0;            // 8*2048*2048 f16 = 2*SH

    const int n4x = (int)(SH / 4);      // float4 count per 16M-elem input
    const int n4w = 1024 * 1024 / 4;    // float4 count per W
    const long long zero = 0;
    const long long M1 = 1024 * 1024;

    // 0) W -> f16
    cast3_kernel<<<dim3(128, 1, 3), 256, 0, stream>>>(Wq, Wk, Wv, wh, wh + M1, wh + 2 * M1, n4w);
    // 1) all three X -> f16 in ONE dispatch
    cast3_kernel<<<dim3(2048, 1, 3), 256, 0, stream>>>(query, keyi, value, slot3, slot0, slot1, n4x);
    // 2) projections (128x128 tile, gx=8, 1024 blocks each)
    gemm_nt_kernel<1><<<dim3(1024, 1, 1), 256, 0, stream>>>(
        slot3, wh, (void*)slot2, 1024, 1024, 1024, 1024, zero, zero, zero, 8);          // q
    gemm_nt_kernel<1><<<dim3(1024, 1, 1), 256, 0, stream>>>(
        slot0, wh + M1, (void*)slot3, 1024, 1024, 1024, 1024, zero, zero, zero, 8);     // k
    gemm_nt_kernel<1><<<dim3(1024, 1, 1), 256, 0, stream>>>(
        slot1, wh + 2 * M1, (void*)slot0, 1024, 1024, 1024, 1024, zero, zero, zero, 8); // v
    // 3) v -> vT (kills wh; wh dead)
    transpose_v_kernel<<<dim3(32, 16, 8), 256, 0, stream>>>(slot0, slot4);
    // 4) S = q @ k^T per batch (overwrites slots 0-1; v and Xv dead)
    gemm_nt_kernel<1><<<dim3(256, 1, 8), 256, 0, stream>>>(
        slot2, slot3, (void*)Pb, 1024, 1024, 1024, 2048,
        (long long)2048 * 1024, (long long)2048 * 1024, (long long)2048 * 2048, 16);
    // 5) P = masked softmax(S), in place
    softmax_kernel<<<dim3(16384), 256, 0, stream>>>(Pb, mask);
    // 6) context = P @ vT^T  (f32 out)
    gemm_nt_kernel<0><<<dim3(128, 1, 8), 256, 0, stream>>>(
        Pb, slot4, (void*)out, 2048, 2048, 2048, 1024,
        (long long)2048 * 2048, (long long)1024 * 2048, (long long)2048 * 1024, 8);
}

// Round 7
// 391.401 us; speedup vs baseline: 1.1844x; 1.0860x over previous
//
#include <hip/hip_runtime.h>
#include <hip/hip_fp16.h>
#include <math.h>

typedef _Float16 f16;
typedef _Float16 f16x4 __attribute__((ext_vector_type(4)));
typedef _Float16 f16x8 __attribute__((ext_vector_type(8)));
typedef float f32x4 __attribute__((ext_vector_type(4)));

#define GLOAD_LDS16(g, l)                                                                  \
    __builtin_amdgcn_global_load_lds((const __attribute__((address_space(1))) void*)(g),   \
                                     (__attribute__((address_space(3))) void*)(l), 16, 0, 0)

// Three-source f32 -> f16 cast with independent destinations, blockIdx.z selects.
__global__ __launch_bounds__(256) void cast3_kernel(const float* __restrict__ s0,
                                                    const float* __restrict__ s1,
                                                    const float* __restrict__ s2,
                                                    f16* d0, f16* d1, f16* d2, int n4each)
{
    const int z = blockIdx.z;
    const float* src = (z == 0) ? s0 : (z == 1) ? s1 : s2;
    f16* d = (z == 0) ? d0 : (z == 1) ? d1 : d2;
    const int stride = gridDim.x * blockDim.x;
    for (int i = blockIdx.x * blockDim.x + threadIdx.x; i < n4each; i += stride) {
        float4 v = *(const float4*)(src + (long long)i * 4);
        *(f16x4*)(d + (long long)i * 4) = (f16x4){(f16)v.x, (f16)v.y, (f16)v.z, (f16)v.w};
    }
}

// ============================================================================
// 256x256 tile NT GEMM, BK=64, 512 threads (8 waves 2Mx4N), 128 KiB LDS dbuf.
// T4 counted vmcnt(8) pipeline, T2 both-sides swizzle (linear LDS dest +
// inverse-swizzled global src + swizzled ds_read), T5 setprio around MFMA.
// C[M,N] = A[M,K](f16) * B[N,K](f16)^T.  M,N % 256 == 0, K % 64 == 0.
// Grid: dim3(nwg, 1, nz), nwg % 8 == 0; gx = N/256.
// ============================================================================
template <int OUTF16>
__global__ __launch_bounds__(512, 1) void gemm_nt_256(
    const f16* __restrict__ Ab, const f16* __restrict__ Bb, void* __restrict__ Cb,
    int K, int lda, int ldb, int ldc,
    long long sA, long long sB, long long sC, int gx)
{
    // [buf][half][128 rows][64 k] f16, linear (global_load_lds writes linearly)
    __shared__ __align__(16) f16 As[2][2][128 * 64];
    __shared__ __align__(16) f16 Bs[2][2][128 * 64];

    // XCD-aware bijective swizzle (nwg % 8 == 0).
    const int nwg = gridDim.x;
    const int swz = (blockIdx.x & 7) * (nwg >> 3) + (blockIdx.x >> 3);
    const int bx = swz % gx, by = swz / gx;

    const int z = blockIdx.z;
    const char* pA = (const char*)(Ab + z * sA + (long long)by * 256 * lda);
    const char* pB = (const char*)(Bb + z * sB + (long long)bx * 256 * ldb);
    const long long lda2 = (long long)lda * 2, ldb2 = (long long)ldb * 2;

    const int tid = threadIdx.x;
    const int w = tid >> 6, l = tid & 63;
    const int wr = w >> 2, wc = w & 3;          // 2 x 4 wave grid

    // --- staging geometry: per (half h, j), thread covers 16B at linear
    // offset (j*512+tid)*16 of the [128][64] half-tile.  row = that>>7.
    // T2: LDS stays linear; global col is inverse-swizzled (XOR involution).
    int rs[2], cs[2];
    rs[0] = tid >> 3;
    rs[1] = (512 + tid) >> 3;
    const int cb = (tid & 7) * 16;
    cs[0] = cb ^ ((rs[0] & 7) << 4);
    cs[1] = cb ^ ((rs[1] & 7) << 4);

#define STAGE_FULL(buf, kt)                                                               \
    do {                                                                                  \
        const long long kb_ = (long long)(kt) * 128;                                      \
        _Pragma("unroll")                                                                 \
        for (int h_ = 0; h_ < 2; h_++) {                                                  \
            _Pragma("unroll")                                                             \
            for (int j_ = 0; j_ < 2; j_++) {                                              \
                GLOAD_LDS16(pA + (long long)(h_ * 128 + rs[j_]) * lda2 + kb_ + cs[j_],    \
                            &As[buf][h_][j_ * 4096 + w * 512]);                           \
                GLOAD_LDS16(pB + (long long)(h_ * 128 + rs[j_]) * ldb2 + kb_ + cs[j_],    \
                            &Bs[buf][h_][j_ * 4096 + w * 512]);                           \
            }                                                                             \
        }                                                                                 \
    } while (0)

    // swizzled frag read: row256 in [0,256), cbyte in [0,128)
#define FRAG(arr, buf, row256, cbyte)                                                     \
    (*(const f16x8*)((const char*)&arr[buf][0][0] + (((row256) >> 7) * 16384) +           \
                     (((row256) & 127) * 128) + ((cbyte) ^ (((row256) & 7) << 4))))

    f32x4 acc[8][4];
#pragma unroll
    for (int i = 0; i < 8; i++)
#pragma unroll
        for (int j = 0; j < 4; j++) acc[i][j] = (f32x4){0.f, 0.f, 0.f, 0.f};

    const int lr = l & 15;          // frag row/col within 16
    const int lkb = (l >> 4) * 16;  // frag k sub-offset in bytes

    const int nt = K >> 6;
    STAGE_FULL(0, 0);
    for (int t = 0; t < nt; ++t) {
        const int buf = t & 1;
        if (t + 1 < nt) {
            STAGE_FULL(buf ^ 1, t + 1);
            asm volatile("s_waitcnt vmcnt(8)" ::: "memory");   // tile t landed; t+1 in flight
        } else {
            asm volatile("s_waitcnt vmcnt(0)" ::: "memory");   // tail drain
        }
        __builtin_amdgcn_s_barrier();                           // publish tile t
        __builtin_amdgcn_sched_barrier(0);

        // B frags for this wave's 64 cols (read once, 8 x ds_read_b128)
        f16x8 bf[4][2];
#pragma unroll
        for (int fc = 0; fc < 4; fc++)
#pragma unroll
            for (int ks = 0; ks < 2; ks++)
                bf[fc][ks] = FRAG(Bs, buf, wc * 64 + fc * 16 + lr, ks * 64 + lkb);

        // 4 phases x {4 ds_read_b128 (A), 16 MFMA}
#pragma unroll
        for (int p = 0; p < 4; p++) {
            f16x8 af[2][2];
#pragma unroll
            for (int fr = 0; fr < 2; fr++)
#pragma unroll
                for (int ks = 0; ks < 2; ks++)
                    af[fr][ks] = FRAG(As, buf, wr * 128 + p * 32 + fr * 16 + lr, ks * 64 + lkb);
            __builtin_amdgcn_s_setprio(1);
#pragma unroll
            for (int fr = 0; fr < 2; fr++)
#pragma unroll
                for (int fc = 0; fc < 4; fc++)
#pragma unroll
                    for (int ks = 0; ks < 2; ks++)
                        acc[p * 2 + fr][fc] = __builtin_amdgcn_mfma_f32_16x16x32_f16(
                            af[fr][ks], bf[fc][ks], acc[p * 2 + fr][fc], 0, 0, 0);
            __builtin_amdgcn_s_setprio(0);
        }

        __builtin_amdgcn_s_barrier();                           // all reads done before overwrite
        __builtin_amdgcn_sched_barrier(0);
    }
#undef STAGE_FULL
#undef FRAG

    // C/D 16x16 layout: col = lane&15, row = (lane>>4)*4 + i  (HW-verified)
    const int row_l = (l >> 4) * 4;
    const long long gr0 = (long long)by * 256 + wr * 128;
    const int gc0 = bx * 256 + wc * 64;
    if (OUTF16) {
        f16* C = (f16*)Cb + z * sC;
#pragma unroll
        for (int fq = 0; fq < 8; fq++)
#pragma unroll
            for (int fc = 0; fc < 4; fc++)
#pragma unroll
                for (int i = 0; i < 4; i++)
                    C[(gr0 + fq * 16 + row_l + i) * ldc + gc0 + fc * 16 + lr] = (f16)acc[fq][fc][i];
    } else {
        float* C = (float*)Cb + z * sC;
#pragma unroll
        for (int fq = 0; fq < 8; fq++)
#pragma unroll
            for (int fc = 0; fc < 4; fc++)
#pragma unroll
                for (int i = 0; i < 4; i++)
                    C[(gr0 + fq * 16 + row_l + i) * ldc + gc0 + fc * 16 + lr] = acc[fq][fc][i];
    }
}

// vT[b][o][s] = v[b][s][o], 64x64 LDS tiles.
__global__ __launch_bounds__(256) void transpose_v_kernel(const f16* __restrict__ v, f16* __restrict__ vT)
{
    __shared__ f16 tile[64][72];
    const int b = blockIdx.z;
    const int s0 = blockIdx.x * 64, o0 = blockIdx.y * 64;
    const int t = threadIdx.x;
    const int r = t >> 2, c = (t & 3) * 16;
    const f16* src = v + ((long long)b * 2048 + s0) * 1024 + o0;
    *(f16x8*)&tile[r][c]     = *(const f16x8*)(src + (long long)r * 1024 + c);
    *(f16x8*)&tile[r][c + 8] = *(const f16x8*)(src + (long long)r * 1024 + c + 8);
    __syncthreads();
    f16* dst = vT + ((long long)b * 1024 + o0) * 2048 + s0;
    f16 buf[16];
#pragma unroll
    for (int j = 0; j < 16; j++) buf[j] = tile[c + j][r];
    *(f16x8*)(dst + (long long)r * 2048 + c)     = *(f16x8*)&buf[0];
    *(f16x8*)(dst + (long long)r * 2048 + c + 8) = *(f16x8*)&buf[8];
}

__device__ __forceinline__ float wred_max(float v) {
#pragma unroll
    for (int o = 32; o > 0; o >>= 1) v = fmaxf(v, __shfl_xor(v, o));
    return v;
}
__device__ __forceinline__ float wred_sum(float v) {
#pragma unroll
    for (int o = 32; o > 0; o >>= 1) v += __shfl_xor(v, o);
    return v;
}

// In-place masked softmax over each 2048-wide score row (fp16).
__global__ __launch_bounds__(256) void softmax_kernel(f16* __restrict__ Sm, const int* __restrict__ mask)
{
    const long long row = blockIdx.x;
    const int b = (int)(row >> 11);
    f16* Srow = Sm + row * 2048;
    const int* mrow = mask + b * 2048;
    const int t = threadIdx.x;
    const int w = t >> 6, l = t & 63;

    f16x8 sv = *(const f16x8*)(Srow + t * 8);
    int4 m0 = *(const int4*)(mrow + t * 8);
    int4 m1 = *(const int4*)(mrow + t * 8 + 4);
    int mk[8] = {m0.x, m0.y, m0.z, m0.w, m1.x, m1.y, m1.z, m1.w};
    float v[8];
#pragma unroll
    for (int j = 0; j < 8; j++) v[j] = (float)sv[j];

    float mx = -INFINITY;
#pragma unroll
    for (int j = 0; j < 8; j++) if (mk[j]) mx = fmaxf(mx, v[j]);
    mx = wred_max(mx);
    __shared__ float redm[4], reds[4];
    if (l == 0) redm[w] = mx;
    __syncthreads();
    mx = fmaxf(fmaxf(redm[0], redm[1]), fmaxf(redm[2], redm[3]));

    if (mx == -INFINITY) {
        // reference: all scores == MASK_FILL -> softmax is exactly uniform
        const f16 u = (f16)(1.0f / 2048.0f);
        f16x8 pv;
#pragma unroll
        for (int j = 0; j < 8; j++) pv[j] = u;
        *(f16x8*)(Srow + t * 8) = pv;
        return;
    }

    float e[8];
    float s = 0.f;
#pragma unroll
    for (int j = 0; j < 8; j++) { e[j] = mk[j] ? expf(v[j] - mx) : 0.f; s += e[j]; }
    s = wred_sum(s);
    if (l == 0) reds[w] = s;
    __syncthreads();
    s = reds[0] + reds[1] + reds[2] + reds[3];
    const float inv = 1.0f / s;
    f16x8 pv;
#pragma unroll
    for (int j = 0; j < 8; j++) pv[j] = (f16)(e[j] * inv);
    *(f16x8*)(Srow + t * 8) = pv;
}

extern "C" void kernel_launch(void* const* d_in, const int* in_sizes, int n_in,
                              void* d_out, int out_size, void* d_ws, size_t ws_size,
                              hipStream_t stream)
{
    const float* query = (const float*)d_in[0];
    const float* keyi  = (const float*)d_in[1];
    const float* value = (const float*)d_in[2];
    const float* Wq    = (const float*)d_in[3];
    const float* Wk    = (const float*)d_in[4];
    const float* Wv    = (const float*)d_in[5];
    const int*   mask  = (const int*)d_in[6];
    float* out = (float*)d_out;

    // ws: 5 slots of SH f16 = 167.8 MB (proven footprint).
    //   slot0: Xk -> v -> P-low ; slot1: Xv -> P-high ; slot2: q ;
    //   slot3: Xq -> k ; slot4: wh (6 MB) -> vT
    const long long SH = (long long)8 * 2048 * 1024;
    f16* slot0 = (f16*)d_ws;
    f16* slot1 = slot0 + SH;
    f16* slot2 = slot0 + 2 * SH;
    f16* slot3 = slot0 + 3 * SH;
    f16* slot4 = slot0 + 4 * SH;
    f16* wh    = slot4;            // dead before transpose writes vT here
    f16* Pb    = slot0;            // 8*2048*2048 f16 = 2*SH

    const int n4x = (int)(SH / 4);
    const int n4w = 1024 * 1024 / 4;
    const long long zero = 0;
    const long long M1 = 1024 * 1024;

    // 0) W -> f16
    cast3_kernel<<<dim3(128, 1, 3), 256, 0, stream>>>(Wq, Wk, Wv, wh, wh + M1, wh + 2 * M1, n4w);
    // 1) all three X -> f16 in one dispatch
    cast3_kernel<<<dim3(2048, 1, 3), 256, 0, stream>>>(query, keyi, value, slot3, slot0, slot1, n4x);
    // 2) projections: M=16384 N=1024 K=1024 -> grid 64*4=256, gx=4
    gemm_nt_256<1><<<dim3(256, 1, 1), 512, 0, stream>>>(
        slot3, wh, (void*)slot2, 1024, 1024, 1024, 1024, zero, zero, zero, 4);          // q
    gemm_nt_256<1><<<dim3(256, 1, 1), 512, 0, stream>>>(
        slot0, wh + M1, (void*)slot3, 1024, 1024, 1024, 1024, zero, zero, zero, 4);     // k
    gemm_nt_256<1><<<dim3(256, 1, 1), 512, 0, stream>>>(
        slot1, wh + 2 * M1, (void*)slot0, 1024, 1024, 1024, 1024, zero, zero, zero, 4); // v
    // 3) v -> vT (kills wh)
    transpose_v_kernel<<<dim3(32, 16, 8), 256, 0, stream>>>(slot0, slot4);
    // 4) S = q @ k^T per batch: M=N=2048 K=1024 -> grid 8*8=64 per z, gx=8
    gemm_nt_256<1><<<dim3(64, 1, 8), 512, 0, stream>>>(
        slot2, slot3, (void*)Pb, 1024, 1024, 1024, 2048,
        (long long)2048 * 1024, (long long)2048 * 1024, (long long)2048 * 2048, 8);
    // 5) P = masked softmax(S), in place
    softmax_kernel<<<dim3(16384), 256, 0, stream>>>(Pb, mask);
    // 6) context = P @ vT^T: M=2048 N=1024 K=2048 -> grid 8*4=32 per z, gx=4
    gemm_nt_256<0><<<dim3(32, 1, 8), 512, 0, stream>>>(
        Pb, slot4, (void*)out, 2048, 2048, 2048, 1024,
        (long long)2048 * 2048, (long long)1024 * 2048, (long long)2048 * 1024, 4);
}